// Round 12
// baseline (274.434 us; speedup 1.0000x reference)
//
#include <hip/hip_runtime.h>
#include <math.h>

#define NN 100000
#define NE 600000
#define CAP 32          // bucket capacity/node; P(Poisson(6) >= 32) ~ 1e-15
#define GN 391          // ceil(NN/256)
#define GEMMB 782       // ceil(NN/128)
#define FILLB 2344      // ceil(NE/256)
// D = 128 fixed

typedef unsigned short u16;
typedef unsigned long long u64;
typedef __attribute__((ext_vector_type(8))) short bf16x8;
typedef __attribute__((ext_vector_type(4))) float f32x4;
typedef __attribute__((ext_vector_type(2))) float f32x2;

union U16x8 { uint4 u; bf16x8 h; };

__device__ __forceinline__ float bflo(unsigned w) { return __uint_as_float(w << 16); }
__device__ __forceinline__ float bfhi(unsigned w) { return __uint_as_float(w & 0xFFFF0000u); }
__device__ __forceinline__ u16 f2bf(float f) {  // round-to-nearest-even
    unsigned u = __float_as_uint(f);
    return (u16)((u + 0x7FFFu + ((u >> 16) & 1u)) >> 16);
}
__device__ __forceinline__ unsigned pack2(float a, float b) {
    return (unsigned)f2bf(a) | ((unsigned)f2bf(b) << 16);
}
__device__ __forceinline__ f32x2 unpk2(unsigned u) {
    f32x2 r; r.x = __uint_as_float(u << 16); r.y = __uint_as_float(u & 0xFFFF0000u);
    return r;
}
// bucket entry: src(17b) << 15 | bf16-weight[14:0] (sign always 0 for ew in [0,1])
__device__ __forceinline__ float bfw(unsigned e) {
    return __uint_as_float((e & 0x7FFFu) << 16);
}
__device__ __forceinline__ int ld_idx(const int* __restrict__ ei, unsigned is32, int pos) {
    return is32 ? ei[pos] : ei[2 * pos];  // int64: little-endian low word
}

// ---------- W -> bf16 fragment-order block (8 blocks of 256 thr per W) ----------
__device__ __forceinline__ void wconv_block(const float* __restrict__ W, u16* __restrict__ Wf,
                                            int blk, int tid) {
    int t = blk * 256 + tid;   // 0..2047
    int lane = t & 63, tile = t >> 6;
    int n = (tile >> 2) * 16 + (lane & 15);
    int k0 = (tile & 3) * 32 + (lane >> 4) * 8;
#pragma unroll
    for (int j = 0; j < 8; ++j) Wf[tile * 512 + lane * 8 + j] = f2bf(W[(k0 + j) * 128 + n]);
}

// ---------- init: zero cursor | detect int32-vs-int64 | wconv W1/W2 ----------
__global__ __launch_bounds__(256) void init_kernel(
    int* __restrict__ cursor, unsigned* __restrict__ flag, const unsigned* __restrict__ ei,
    const float* __restrict__ W1, const float* __restrict__ W2,
    u16* __restrict__ Wf1, u16* __restrict__ Wf2)
{
    __shared__ unsigned red[256];
    int b = blockIdx.x, tid = threadIdx.x;
    if (b < GN) {
        int i = b * 256 + tid;
        if (i < NN) cursor[i] = 0;
    } else if (b == GN) {
        unsigned v = 0;
        for (int i = tid; i < 4096; i += 256) v |= ei[2 * i + 1];
        red[tid] = v;
        __syncthreads();
        for (int o = 128; o > 0; o >>= 1) {
            if (tid < o) red[tid] |= red[tid + o];
            __syncthreads();
        }
        if (tid == 0) *flag = red[0] ? 1u : 0u;   // nonzero -> int32 storage
    } else if (b <= GN + 8) {
        wconv_block(W1, Wf1, b - GN - 1, tid);
    } else {
        wconv_block(W2, Wf2, b - GN - 9, tid);
    }
}

// ---------- transposed MFMA gemm body: H = X @ W (no LDS, no barrier) ----------
// (X@W)^T = W^T @ X^T per 16x16 tile: A-frag = Wf, B-frag = X rows direct from global.
// D: lane holds 4 consecutive channels (ct*16+q*4..+3) of node (base+mt*16+m) -> 8B stores.
template <bool F32IN>
__device__ __forceinline__ void gemmT_body(int gb, const void* __restrict__ Xv,
                                           const u16* __restrict__ Wf, u16* __restrict__ H) {
    const int tid = threadIdx.x;
    const int wave = tid >> 6, lane = tid & 63;
    const int m = lane & 15, q = lane >> 4;
    const unsigned nodeBase = gb * 128 + wave * 32;

    U16x8 xf[2][4];
#pragma unroll
    for (int mt = 0; mt < 2; ++mt) {
        unsigned row = nodeBase + mt * 16 + m;
        unsigned rowc = row < NN ? row : NN - 1;
        if (F32IN) {
#pragma unroll
            for (int kc = 0; kc < 4; ++kc) {
                float4 a = ((const float4*)Xv)[rowc * 32u + kc * 8 + q * 2];
                float4 b = ((const float4*)Xv)[rowc * 32u + kc * 8 + q * 2 + 1];
                xf[mt][kc].u = make_uint4(pack2(a.x, a.y), pack2(a.z, a.w),
                                          pack2(b.x, b.y), pack2(b.z, b.w));
            }
        } else {
#pragma unroll
            for (int kc = 0; kc < 4; ++kc)
                xf[mt][kc].u = ((const uint4*)Xv)[rowc * 16u + kc * 4 + q];
        }
    }

#pragma unroll
    for (int ct = 0; ct < 8; ++ct) {
        U16x8 wfr[4];
#pragma unroll
        for (int kc = 0; kc < 4; ++kc)
            wfr[kc].u = ((const uint4*)Wf)[(ct * 4 + kc) * 64 + lane];
#pragma unroll
        for (int mt = 0; mt < 2; ++mt) {
            f32x4 acc = (f32x4){0.f, 0.f, 0.f, 0.f};
#pragma unroll
            for (int kc = 0; kc < 4; ++kc)
                acc = __builtin_amdgcn_mfma_f32_16x16x32_bf16(
                    wfr[kc].h, xf[mt][kc].h, acc, 0, 0, 0);
            unsigned node = nodeBase + mt * 16 + m;
            if (node < NN) {
                uint2 o = make_uint2(pack2(acc[0], acc[1]), pack2(acc[2], acc[3]));
                *(uint2*)&H[(size_t)node * 128 + ct * 16 + q * 4] = o;
            }
        }
    }
}

// ---------- fused fill + gemm1 (independent roles, 3:1 interleave) ----------
// fill: ONE u32 cursor atomic per edge + 4B bucket store (latency-bound, hidden under gemm).
// gemm: H1 = w_x @ W1 (UNSCALED; dinv scale applied later by unpackScale).
__global__ __launch_bounds__(256) void fillgemm1_kernel(
    const int* __restrict__ ei, const unsigned* __restrict__ flag,
    const float* __restrict__ ew, int* __restrict__ cursor, unsigned* __restrict__ bucket,
    const float* __restrict__ w_x, const u16* __restrict__ Wf1, u16* __restrict__ H1)
{
    int b = blockIdx.x;
    if ((b & 3) == 0) {
        gemmT_body<true>(b >> 2, w_x, Wf1, H1);
        return;
    }
    int fid = (b >> 2) * 3 + (b & 3) - 1;
    if (fid >= FILLB) return;
    int e = fid * 256 + threadIdx.x;
    if (e < NE) {
        unsigned is32 = *flag;
        int s = ld_idx(ei, is32, e);
        int d = ld_idx(ei, is32, NE + e);
        unsigned wq = (unsigned)f2bf(ew[e]) & 0x7FFFu;   // bf16, sign bit 0
        int slot = atomicAdd(&cursor[d], 1);
        if (slot < CAP) bucket[(size_t)d * CAP + slot] = ((unsigned)s << 15) | wq;
    }
}

// ---------- unpackScale: degree->dinv from buckets + in-place H1 row scale ----------
// 16 lanes/node: reduce bucket weights (stride 16), dinv=rsqrt(deg+1); then each lane
// scales one uint4 (8 ch) of H1[n] -> H1' = dinv[n]*H1[n]. Fully coalesced.
__global__ __launch_bounds__(256) void unpackScale_kernel(
    int* __restrict__ cursor, const unsigned* __restrict__ bucket,
    float* __restrict__ dinv, u16* __restrict__ H1)
{
    unsigned t = blockIdx.x * 256 + threadIdx.x;
    unsigned n = t >> 4;
    unsigned ln = t & 15;
    int c = cursor[n];
    if (c > CAP) c = CAP;
    float s = 0.f;
    const size_t base = (size_t)n * CAP;
    for (int i = (int)ln; i < c; i += 16) s += bfw(bucket[base + i]);
#pragma unroll
    for (int off = 8; off > 0; off >>= 1) s += __shfl_down(s, off, 16);
    float dv;
    if (ln == 0) {
        cursor[n] = c;
        dv = rsqrtf(s + 1.0f);
        dinv[n] = dv;
    }
    dv = __shfl(dv, 0, 16);
    uint4* Hr = (uint4*)H1;
    uint4 u = Hr[n * 16u + ln];
    u.x = pack2(bflo(u.x) * dv, bfhi(u.x) * dv);
    u.y = pack2(bflo(u.y) * dv, bfhi(u.y) * dv);
    u.z = pack2(bflo(u.z) * dv, bfhi(u.z) * dv);
    u.w = pack2(bflo(u.w) * dv, bfhi(u.w) * dv);
    Hr[n * 16u + ln] = u;
}

// gemm2: H2' = X1' @ W2  (X1' already relu'd and dinv-scaled by agg1)
__global__ __launch_bounds__(256) void gemm2_kernel(
    const u16* __restrict__ X, const u16* __restrict__ Wf, u16* __restrict__ H)
{
    gemmT_body<false>(blockIdx.x, X, Wf, H);
}

// ---------- agg: 1 wave/node, straight-line 3 slots (deg<=12) + rare tail ----------
// lane = eo*16 + cg. row = dinv[n]*(sum w*H'[src] + H'[n]) + bias.
// HEAD=false: store relu(row)*dinv[n] bf16. HEAD=true: out[n] = relu(row).Wl + bl.
template <bool HEAD>
__global__ __launch_bounds__(256) void agg_kernel(
    const int* __restrict__ cnt, const unsigned* __restrict__ bucket,
    const u16* __restrict__ H, const float* __restrict__ dinv,
    const float* __restrict__ bias, const float* __restrict__ Wl,
    const float* __restrict__ bl, u16* __restrict__ X, float* __restrict__ out)
{
    unsigned t = blockIdx.x * 256 + threadIdx.x;
    unsigned n = t >> 6;
    unsigned lane = t & 63;
    unsigned cg = lane & 15;
    unsigned eo = lane >> 4;

    const int c = cnt[n];
    const unsigned base = n * CAP;
    const uint4* Hr = (const uint4*)H;

    unsigned e0 = bucket[base + eo];
    unsigned e1 = bucket[base + eo + 4];
    unsigned e2 = bucket[base + eo + 8];
    float w0 = ((int)eo      < c) ? bfw(e0) : 0.f;
    float w1 = ((int)eo + 4  < c) ? bfw(e1) : 0.f;
    float w2 = ((int)eo + 8  < c) ? bfw(e2) : 0.f;
    unsigned s0 = e0 >> 15; if (s0 > NN - 1) s0 = NN - 1;
    unsigned s1 = e1 >> 15; if (s1 > NN - 1) s1 = NN - 1;
    unsigned s2 = e2 >> 15; if (s2 > NN - 1) s2 = NN - 1;
    uint4 u0 = Hr[s0 * 16u + cg];
    uint4 u1 = Hr[s1 * 16u + cg];
    uint4 u2 = Hr[s2 * 16u + cg];

    f32x2 a0 = {0.f, 0.f}, a1 = {0.f, 0.f}, a2 = {0.f, 0.f}, a3 = {0.f, 0.f};
#define ACC4(U, WS)                                                     \
    {   f32x2 wv; wv.x = WS; wv.y = WS;                                 \
        a0 = __builtin_elementwise_fma(unpk2((U).x), wv, a0);           \
        a1 = __builtin_elementwise_fma(unpk2((U).y), wv, a1);           \
        a2 = __builtin_elementwise_fma(unpk2((U).z), wv, a2);           \
        a3 = __builtin_elementwise_fma(unpk2((U).w), wv, a3); }
    ACC4(u0, w0) ACC4(u1, w1) ACC4(u2, w2)

    if (c > 12) {                 // rare tail
        for (int i = (int)eo + 12; i < c; i += 4) {
            unsigned e = bucket[base + i];
            float w = bfw(e);
            unsigned s = e >> 15; if (s > NN - 1) s = NN - 1;
            uint4 u = Hr[s * 16u + cg];
            ACC4(u, w)
        }
    }
#undef ACC4

    float acc[8] = {a0.x, a0.y, a1.x, a1.y, a2.x, a2.y, a3.x, a3.y};
#pragma unroll
    for (int j = 0; j < 8; ++j) {
        acc[j] += __shfl_down(acc[j], 32);
        acc[j] += __shfl_down(acc[j], 16);
    }

    float d = 0.f;
    if (lane < 16) {
        float dnv = dinv[n];
        uint4 hn = Hr[n * 16u + cg];          // self-loop: H'[n]
        float4 b0 = ((const float4*)bias)[cg * 2];
        float4 b1 = ((const float4*)bias)[cg * 2 + 1];
        acc[0] += bflo(hn.x); acc[1] += bfhi(hn.x);
        acc[2] += bflo(hn.y); acc[3] += bfhi(hn.y);
        acc[4] += bflo(hn.z); acc[5] += bfhi(hn.z);
        acc[6] += bflo(hn.w); acc[7] += bfhi(hn.w);
        float v[8];
        v[0] = fmaxf(fmaf(dnv, acc[0], b0.x), 0.f);
        v[1] = fmaxf(fmaf(dnv, acc[1], b0.y), 0.f);
        v[2] = fmaxf(fmaf(dnv, acc[2], b0.z), 0.f);
        v[3] = fmaxf(fmaf(dnv, acc[3], b0.w), 0.f);
        v[4] = fmaxf(fmaf(dnv, acc[4], b1.x), 0.f);
        v[5] = fmaxf(fmaf(dnv, acc[5], b1.y), 0.f);
        v[6] = fmaxf(fmaf(dnv, acc[6], b1.z), 0.f);
        v[7] = fmaxf(fmaf(dnv, acc[7], b1.w), 0.f);
        if (HEAD) {
            float4 w0v = ((const float4*)Wl)[cg * 2];
            float4 w1v = ((const float4*)Wl)[cg * 2 + 1];
            d = v[0] * w0v.x + v[1] * w0v.y + v[2] * w0v.z + v[3] * w0v.w
              + v[4] * w1v.x + v[5] * w1v.y + v[6] * w1v.z + v[7] * w1v.w;
        } else {
            uint4 o;
            o.x = pack2(v[0] * dnv, v[1] * dnv); o.y = pack2(v[2] * dnv, v[3] * dnv);
            o.z = pack2(v[4] * dnv, v[5] * dnv); o.w = pack2(v[6] * dnv, v[7] * dnv);
            ((uint4*)X)[n * 16u + cg] = o;
        }
    }
    if (HEAD) {
#pragma unroll
        for (int off = 8; off > 0; off >>= 1) d += __shfl_down(d, off, 16);
        if (lane == 0) out[n] = d + bl[0];
    }
}

extern "C" void kernel_launch(void* const* d_in, const int* in_sizes, int n_in,
                              void* d_out, int out_size, void* d_ws, size_t ws_size,
                              hipStream_t stream) {
    const float* w_x = (const float*)d_in[0];
    const int*   ei  = (const int*)d_in[1];
    const float* ew  = (const float*)d_in[2];
    const float* W1  = (const float*)d_in[3];
    const float* b1  = (const float*)d_in[4];
    const float* W2  = (const float*)d_in[5];
    const float* b2  = (const float*)d_in[6];
    const float* Wl  = (const float*)d_in[7];
    const float* bl  = (const float*)d_in[8];
    float* out = (float*)d_out;

    // ws: H1[NN*128 bf16] H2[NN*128 bf16] Xb[NN*128 bf16] flag(+pad) dinv[NN]
    //     cursor[NN] bucket[NN*CAP u32] Wf1/Wf2[16384 u16]   (~91 MB)
    u16*      H1   = (u16*)d_ws;
    u16*      H2   = H1 + (size_t)NN * 128;
    u16*      Xb   = H2 + (size_t)NN * 128;
    unsigned* flag = (unsigned*)(Xb + (size_t)NN * 128);
    float*    dinv = (float*)(flag + 2);
    int*      cursor = (int*)(dinv + NN);
    unsigned* bucket = (unsigned*)(cursor + NN);
    u16*      Wf1  = (u16*)(bucket + (size_t)NN * CAP);
    u16*      Wf2  = Wf1 + 16384;

    const int BLK = 256;
    const int GA  = NN * 64 / BLK;     // 25000 agg blocks
    const int GU  = NN * 16 / BLK;     // 6250 unpackScale blocks
    const int GF  = 4 * GEMMB;         // 3128 fused blocks (782 gemm + 2346 fill slots)

    init_kernel<<<GN + 17, BLK, 0, stream>>>(cursor, flag, (const unsigned*)ei,
                                             W1, W2, Wf1, Wf2);
    fillgemm1_kernel<<<GF, BLK, 0, stream>>>(ei, flag, ew, cursor, bucket, w_x, Wf1, H1);
    unpackScale_kernel<<<GU, BLK, 0, stream>>>(cursor, bucket, dinv, H1);
    agg_kernel<false><<<GA, BLK, 0, stream>>>(cursor, bucket, H1, dinv, b1,
                                              nullptr, nullptr, Xb, nullptr);
    gemm2_kernel<<<GEMMB, BLK, 0, stream>>>(Xb, Wf2, H2);
    agg_kernel<true><<<GA, BLK, 0, stream>>>(cursor, bucket, H2, dinv, b2,
                                             Wl, bl, nullptr, out);
}

// Round 13
// 248.894 us; speedup vs baseline: 1.1026x; 1.1026x over previous
//
#include <hip/hip_runtime.h>
#include <math.h>

#define NN 100000
#define NE 600000
#define CAP 32          // bucket capacity/node; P(Poisson(6) >= 32) ~ 1e-15
#define GEMMB 782       // ceil(NN/128)
#define FILLB 2344      // ceil(NE/256)
// D = 128 fixed

typedef unsigned short u16;
typedef unsigned long long u64;
typedef __attribute__((ext_vector_type(8))) short bf16x8;
typedef __attribute__((ext_vector_type(4))) float f32x4;
typedef __attribute__((ext_vector_type(2))) float f32x2;

union U16x8 { uint4 u; bf16x8 h; };

__device__ __forceinline__ float bflo(unsigned w) { return __uint_as_float(w << 16); }
__device__ __forceinline__ float bfhi(unsigned w) { return __uint_as_float(w & 0xFFFF0000u); }
__device__ __forceinline__ u16 f2bf(float f) {  // round-to-nearest-even
    unsigned u = __float_as_uint(f);
    return (u16)((u + 0x7FFFu + ((u >> 16) & 1u)) >> 16);
}
__device__ __forceinline__ unsigned pack2(float a, float b) {
    return (unsigned)f2bf(a) | ((unsigned)f2bf(b) << 16);
}
__device__ __forceinline__ f32x2 unpk2(unsigned u) {
    f32x2 r; r.x = __uint_as_float(u << 16); r.y = __uint_as_float(u & 0xFFFF0000u);
    return r;
}
// bucket entry: src(17b) << 15 | bf16-weight[14:0] (sign always 0 for ew in [0,1])
__device__ __forceinline__ float bfw(unsigned e) {
    return __uint_as_float((e & 0x7FFFu) << 16);
}
__device__ __forceinline__ int ld_idx(const int* __restrict__ ei, unsigned is32, int pos) {
    return is32 ? ei[pos] : ei[2 * pos];  // int64: little-endian low word
}

// ---------- W -> bf16 fragment-order block (8 blocks of 256 thr per W) ----------
// Tile (ct,kc): lane holds W[kc*32+(lane>>4)*8+j][ct*16+(lane&15)], j=0..7.
__device__ __forceinline__ void wconv_block(const float* __restrict__ W, u16* __restrict__ Wf,
                                            int blk, int tid) {
    int t = blk * 256 + tid;   // 0..2047
    int lane = t & 63, tile = t >> 6;
    int n = (tile >> 2) * 16 + (lane & 15);
    int k0 = (tile & 3) * 32 + (lane >> 4) * 8;
#pragma unroll
    for (int j = 0; j < 8; ++j) Wf[tile * 512 + lane * 8 + j] = f2bf(W[(k0 + j) * 128 + n]);
}

// ---------- init: detect int32-vs-int64 | wconv W1/W2 (cursor zeroed by memset) ----------
__global__ __launch_bounds__(256) void init_kernel(
    unsigned* __restrict__ flag, const unsigned* __restrict__ ei,
    const float* __restrict__ W1, const float* __restrict__ W2,
    u16* __restrict__ Wf1, u16* __restrict__ Wf2)
{
    __shared__ unsigned red[256];
    int b = blockIdx.x, tid = threadIdx.x;
    if (b == 0) {
        unsigned v = 0;
        for (int i = tid; i < 4096; i += 256) v |= ei[2 * i + 1];
        red[tid] = v;
        __syncthreads();
        for (int o = 128; o > 0; o >>= 1) {
            if (tid < o) red[tid] |= red[tid + o];
            __syncthreads();
        }
        if (tid == 0) *flag = red[0] ? 1u : 0u;   // nonzero -> int32 storage
    } else if (b <= 8) {
        wconv_block(W1, Wf1, b - 1, tid);
    } else {
        wconv_block(W2, Wf2, b - 9, tid);
    }
}

// ---------- fill: ONE u32 cursor atomic per edge + 4B bucket store ----------
// Runs ALONE: its cursor/bucket working set must own the L2 (r7/r12 lesson).
__global__ __launch_bounds__(256) void fill_kernel(
    const int* __restrict__ ei, const unsigned* __restrict__ flag,
    const float* __restrict__ ew, int* __restrict__ cursor, unsigned* __restrict__ bucket)
{
    int e = blockIdx.x * 256 + threadIdx.x;
    if (e < NE) {
        unsigned is32 = *flag;
        int s = ld_idx(ei, is32, e);
        int d = ld_idx(ei, is32, NE + e);
        unsigned wq = (unsigned)f2bf(ew[e]) & 0x7FFFu;   // bf16, sign bit 0
        int slot = atomicAdd(&cursor[d], 1);
        if (slot < CAP) bucket[(size_t)d * CAP + slot] = ((unsigned)s << 15) | wq;
    }
}

// ---------- unpack: weighted degree from buckets (coalesced), dinv, clamp cursor ----------
__global__ __launch_bounds__(256) void unpack_kernel(
    int* __restrict__ cursor, const unsigned* __restrict__ bucket, float* __restrict__ dinv)
{
    unsigned t = blockIdx.x * 256 + threadIdx.x;
    unsigned n = t >> 4;
    unsigned ln = t & 15;
    int c = cursor[n];
    if (c > CAP) c = CAP;
    float s = 0.f;
    const size_t base = (size_t)n * CAP;
    for (int i = (int)ln; i < c; i += 16) s += bfw(bucket[base + i]);
#pragma unroll
    for (int off = 8; off > 0; off >>= 1) s += __shfl_down(s, off, 16);
    if (ln == 0) {
        cursor[n] = c;
        dinv[n] = rsqrtf(s + 1.0f);
    }
}

// ---------- transposed MFMA gemm: H = (F32IN? diag(dinv):(I)) * (X @ W) ----------
// (X@W)^T = W^T @ X^T per 16x16 tile: A-frag = Wf, B-frag = X rows direct from global.
// D: lane holds 4 consecutive channels of one node -> 8B coalesced stores. No LDS/barrier.
template <bool F32IN>
__global__ __launch_bounds__(256) void gemmT_kernel(
    const void* __restrict__ Xv, const u16* __restrict__ Wf, u16* __restrict__ H,
    const float* __restrict__ dinv)
{
    const int tid = threadIdx.x;
    const int wave = tid >> 6, lane = tid & 63;
    const int m = lane & 15, q = lane >> 4;
    const unsigned nodeBase = blockIdx.x * 128 + wave * 32;

    U16x8 xf[2][4];
    float dn[2];
#pragma unroll
    for (int mt = 0; mt < 2; ++mt) {
        unsigned row = nodeBase + mt * 16 + m;
        unsigned rowc = row < NN ? row : NN - 1;
        if (F32IN) {
            dn[mt] = dinv[rowc];
#pragma unroll
            for (int kc = 0; kc < 4; ++kc) {
                float4 a = ((const float4*)Xv)[rowc * 32u + kc * 8 + q * 2];
                float4 b = ((const float4*)Xv)[rowc * 32u + kc * 8 + q * 2 + 1];
                xf[mt][kc].u = make_uint4(pack2(a.x, a.y), pack2(a.z, a.w),
                                          pack2(b.x, b.y), pack2(b.z, b.w));
            }
        } else {
#pragma unroll
            for (int kc = 0; kc < 4; ++kc)
                xf[mt][kc].u = ((const uint4*)Xv)[rowc * 16u + kc * 4 + q];
        }
    }

#pragma unroll
    for (int ct = 0; ct < 8; ++ct) {
        U16x8 wfr[4];
#pragma unroll
        for (int kc = 0; kc < 4; ++kc)
            wfr[kc].u = ((const uint4*)Wf)[(ct * 4 + kc) * 64 + lane];
#pragma unroll
        for (int mt = 0; mt < 2; ++mt) {
            f32x4 acc = (f32x4){0.f, 0.f, 0.f, 0.f};
#pragma unroll
            for (int kc = 0; kc < 4; ++kc)
                acc = __builtin_amdgcn_mfma_f32_16x16x32_bf16(
                    wfr[kc].h, xf[mt][kc].h, acc, 0, 0, 0);
            unsigned node = nodeBase + mt * 16 + m;
            if (node < NN) {
                float s = F32IN ? dn[mt] : 1.0f;
                uint2 o = make_uint2(pack2(acc[0] * s, acc[1] * s),
                                     pack2(acc[2] * s, acc[3] * s));
                *(uint2*)&H[(size_t)node * 128 + ct * 16 + q * 4] = o;
            }
        }
    }
}

// ---------- agg: 1 wave/node, straight-line 4 slots (deg<=16) + rare tail ----------
// lane = eo*16 + cg. row = dinv[n]*(sum w*H'[src] + H'[n]) + bias.
// Self-loop row + dinv issued early (same memory epoch as the gathers).
// HEAD=false: store relu(row)*dinv[n] bf16. HEAD=true: out[n] = relu(row).Wl + bl.
template <bool HEAD>
__global__ __launch_bounds__(256) void agg_kernel(
    const int* __restrict__ cnt, const unsigned* __restrict__ bucket,
    const u16* __restrict__ H, const float* __restrict__ dinv,
    const float* __restrict__ bias, const float* __restrict__ Wl,
    const float* __restrict__ bl, u16* __restrict__ X, float* __restrict__ out)
{
    unsigned t = blockIdx.x * 256 + threadIdx.x;
    unsigned n = t >> 6;
    unsigned lane = t & 63;
    unsigned cg = lane & 15;
    unsigned eo = lane >> 4;

    const int c = cnt[n];
    const unsigned base = n * CAP;
    const uint4* Hr = (const uint4*)H;

    // early issue: self-loop row + dinv (all lanes; quarter-wave broadcast)
    uint4 hn = Hr[n * 16u + cg];
    float dnv = dinv[n];

    // slots eo, eo+4, eo+8, eo+12 (max 15 < CAP); invalid slots: w=0, poison src
    // clamps to a single L2-hot row -> near-free.
    unsigned e0 = bucket[base + eo];
    unsigned e1 = bucket[base + eo + 4];
    unsigned e2 = bucket[base + eo + 8];
    unsigned e3 = bucket[base + eo + 12];
    float w0 = ((int)eo      < c) ? bfw(e0) : 0.f;
    float w1 = ((int)eo + 4  < c) ? bfw(e1) : 0.f;
    float w2 = ((int)eo + 8  < c) ? bfw(e2) : 0.f;
    float w3 = ((int)eo + 12 < c) ? bfw(e3) : 0.f;
    unsigned s0 = e0 >> 15; if (s0 > NN - 1) s0 = NN - 1;
    unsigned s1 = e1 >> 15; if (s1 > NN - 1) s1 = NN - 1;
    unsigned s2 = e2 >> 15; if (s2 > NN - 1) s2 = NN - 1;
    unsigned s3 = e3 >> 15; if (s3 > NN - 1) s3 = NN - 1;
    uint4 u0 = Hr[s0 * 16u + cg];
    uint4 u1 = Hr[s1 * 16u + cg];
    uint4 u2 = Hr[s2 * 16u + cg];
    uint4 u3 = Hr[s3 * 16u + cg];

    f32x2 a0 = {0.f, 0.f}, a1 = {0.f, 0.f}, a2 = {0.f, 0.f}, a3 = {0.f, 0.f};
#define ACC4(U, WS)                                                     \
    {   f32x2 wv; wv.x = WS; wv.y = WS;                                 \
        a0 = __builtin_elementwise_fma(unpk2((U).x), wv, a0);           \
        a1 = __builtin_elementwise_fma(unpk2((U).y), wv, a1);           \
        a2 = __builtin_elementwise_fma(unpk2((U).z), wv, a2);           \
        a3 = __builtin_elementwise_fma(unpk2((U).w), wv, a3); }
    ACC4(u0, w0) ACC4(u1, w1) ACC4(u2, w2) ACC4(u3, w3)

    if (c > 16) {                 // very rare tail (P ~ 1e-4 of nodes)
        for (int i = (int)eo + 16; i < c; i += 4) {
            unsigned e = bucket[base + i];
            float w = bfw(e);
            unsigned s = e >> 15; if (s > NN - 1) s = NN - 1;
            uint4 u = Hr[s * 16u + cg];
            ACC4(u, w)
        }
    }
#undef ACC4

    float acc[8] = {a0.x, a0.y, a1.x, a1.y, a2.x, a2.y, a3.x, a3.y};
#pragma unroll
    for (int j = 0; j < 8; ++j) {
        acc[j] += __shfl_down(acc[j], 32);
        acc[j] += __shfl_down(acc[j], 16);
    }

    float d = 0.f;
    if (lane < 16) {
        float4 b0 = ((const float4*)bias)[cg * 2];
        float4 b1 = ((const float4*)bias)[cg * 2 + 1];
        acc[0] += bflo(hn.x); acc[1] += bfhi(hn.x);
        acc[2] += bflo(hn.y); acc[3] += bfhi(hn.y);
        acc[4] += bflo(hn.z); acc[5] += bfhi(hn.z);
        acc[6] += bflo(hn.w); acc[7] += bfhi(hn.w);
        float v[8];
        v[0] = fmaxf(fmaf(dnv, acc[0], b0.x), 0.f);
        v[1] = fmaxf(fmaf(dnv, acc[1], b0.y), 0.f);
        v[2] = fmaxf(fmaf(dnv, acc[2], b0.z), 0.f);
        v[3] = fmaxf(fmaf(dnv, acc[3], b0.w), 0.f);
        v[4] = fmaxf(fmaf(dnv, acc[4], b1.x), 0.f);
        v[5] = fmaxf(fmaf(dnv, acc[5], b1.y), 0.f);
        v[6] = fmaxf(fmaf(dnv, acc[6], b1.z), 0.f);
        v[7] = fmaxf(fmaf(dnv, acc[7], b1.w), 0.f);
        if (HEAD) {
            float4 w0v = ((const float4*)Wl)[cg * 2];
            float4 w1v = ((const float4*)Wl)[cg * 2 + 1];
            d = v[0] * w0v.x + v[1] * w0v.y + v[2] * w0v.z + v[3] * w0v.w
              + v[4] * w1v.x + v[5] * w1v.y + v[6] * w1v.z + v[7] * w1v.w;
        } else {
            // store X1' = relu(row) * dinv[n]  (pre-scales gemm2's output)
            uint4 o;
            o.x = pack2(v[0] * dnv, v[1] * dnv); o.y = pack2(v[2] * dnv, v[3] * dnv);
            o.z = pack2(v[4] * dnv, v[5] * dnv); o.w = pack2(v[6] * dnv, v[7] * dnv);
            ((uint4*)X)[n * 16u + cg] = o;
        }
    }
    if (HEAD) {
#pragma unroll
        for (int off = 8; off > 0; off >>= 1) d += __shfl_down(d, off, 16);
        if (lane == 0) out[n] = d + bl[0];
    }
}

extern "C" void kernel_launch(void* const* d_in, const int* in_sizes, int n_in,
                              void* d_out, int out_size, void* d_ws, size_t ws_size,
                              hipStream_t stream) {
    const float* w_x = (const float*)d_in[0];
    const int*   ei  = (const int*)d_in[1];
    const float* ew  = (const float*)d_in[2];
    const float* W1  = (const float*)d_in[3];
    const float* b1  = (const float*)d_in[4];
    const float* W2  = (const float*)d_in[5];
    const float* b2  = (const float*)d_in[6];
    const float* Wl  = (const float*)d_in[7];
    const float* bl  = (const float*)d_in[8];
    float* out = (float*)d_out;

    // ws: H1[NN*128 bf16] H2[NN*128 bf16] Xb[NN*128 bf16] flag(+pad) dinv[NN]
    //     cursor[NN] bucket[NN*CAP u32] Wf1/Wf2[16384 u16]   (~91 MB)
    u16*      H1   = (u16*)d_ws;
    u16*      H2   = H1 + (size_t)NN * 128;
    u16*      Xb   = H2 + (size_t)NN * 128;
    unsigned* flag = (unsigned*)(Xb + (size_t)NN * 128);
    float*    dinv = (float*)(flag + 2);
    int*      cursor = (int*)(dinv + NN);
    unsigned* bucket = (unsigned*)(cursor + NN);
    u16*      Wf1  = (u16*)(bucket + (size_t)NN * CAP);
    u16*      Wf2  = Wf1 + 16384;

    const int BLK = 256;
    const int GA  = NN * 64 / BLK;     // 25000 agg blocks
    const int GU  = NN * 16 / BLK;     // 6250 unpack blocks

    hipMemsetAsync(cursor, 0, (size_t)NN * sizeof(int), stream);
    init_kernel<<<17, BLK, 0, stream>>>(flag, (const unsigned*)ei, W1, W2, Wf1, Wf2);
    fill_kernel<<<FILLB, BLK, 0, stream>>>(ei, flag, ew, cursor, bucket);
    unpack_kernel<<<GU, BLK, 0, stream>>>(cursor, bucket, dinv);
    gemmT_kernel<true><<<GEMMB, BLK, 0, stream>>>(w_x, Wf1, H1, dinv);
    agg_kernel<false><<<GA, BLK, 0, stream>>>(cursor, bucket, H1, dinv, b1,
                                              nullptr, nullptr, Xb, nullptr);
    gemmT_kernel<false><<<GEMMB, BLK, 0, stream>>>(Xb, Wf2, H2, nullptr);
    agg_kernel<true><<<GA, BLK, 0, stream>>>(cursor, bucket, H2, dinv, b2,
                                             Wl, bl, nullptr, out);
}

// Round 14
// 241.934 us; speedup vs baseline: 1.1343x; 1.0288x over previous
//
#include <hip/hip_runtime.h>
#include <math.h>

#define NN 100000
#define NE 600000
#define CAP 32          // bucket capacity/node; P(Poisson(6) >= 32) ~ 1e-15
#define GN 391          // ceil(NN/256)
#define GEMMB 782       // ceil(NN/128)
#define FILLB 2344      // ceil(NE/256)
// D = 128 fixed

typedef unsigned short u16;
typedef unsigned long long u64;
typedef __attribute__((ext_vector_type(8))) short bf16x8;
typedef __attribute__((ext_vector_type(4))) float f32x4;
typedef __attribute__((ext_vector_type(2))) float f32x2;

union U16x8 { uint4 u; bf16x8 h; };

__device__ __forceinline__ float bflo(unsigned w) { return __uint_as_float(w << 16); }
__device__ __forceinline__ float bfhi(unsigned w) { return __uint_as_float(w & 0xFFFF0000u); }
__device__ __forceinline__ u16 f2bf(float f) {  // round-to-nearest-even
    unsigned u = __float_as_uint(f);
    return (u16)((u + 0x7FFFu + ((u >> 16) & 1u)) >> 16);
}
__device__ __forceinline__ unsigned pack2(float a, float b) {
    return (unsigned)f2bf(a) | ((unsigned)f2bf(b) << 16);
}
__device__ __forceinline__ f32x2 unpk2(unsigned u) {
    f32x2 r; r.x = __uint_as_float(u << 16); r.y = __uint_as_float(u & 0xFFFF0000u);
    return r;
}
// bucket entry: src(17b) << 15 | bf16-weight[14:0] (sign always 0 for ew in [0,1])
__device__ __forceinline__ float bfw(unsigned e) {
    return __uint_as_float((e & 0x7FFFu) << 16);
}
__device__ __forceinline__ int ld_idx(const int* __restrict__ ei, unsigned is32, int pos) {
    return is32 ? ei[pos] : ei[2 * pos];  // int64: little-endian low word
}

// ---------- W -> bf16 fragment-order block (8 blocks of 256 thr per W) ----------
// Tile (ct,kc): lane holds W[kc*32+(lane>>4)*8+j][ct*16+(lane&15)], j=0..7.
__device__ __forceinline__ void wconv_block(const float* __restrict__ W, u16* __restrict__ Wf,
                                            int blk, int tid) {
    int t = blk * 256 + tid;   // 0..2047
    int lane = t & 63, tile = t >> 6;
    int n = (tile >> 2) * 16 + (lane & 15);
    int k0 = (tile & 3) * 32 + (lane >> 4) * 8;
#pragma unroll
    for (int j = 0; j < 8; ++j) Wf[tile * 512 + lane * 8 + j] = f2bf(W[(k0 + j) * 128 + n]);
}

// ---------- init: zero cursor | detect int32-vs-int64 | wconv W1/W2 ----------
__global__ __launch_bounds__(256) void init_kernel(
    int* __restrict__ cursor, unsigned* __restrict__ flag, const unsigned* __restrict__ ei,
    const float* __restrict__ W1, const float* __restrict__ W2,
    u16* __restrict__ Wf1, u16* __restrict__ Wf2)
{
    __shared__ unsigned red[256];
    int b = blockIdx.x, tid = threadIdx.x;
    if (b < GN) {
        int i = b * 256 + tid;
        if (i < NN) cursor[i] = 0;
    } else if (b == GN) {
        unsigned v = 0;
        for (int i = tid; i < 4096; i += 256) v |= ei[2 * i + 1];
        red[tid] = v;
        __syncthreads();
        for (int o = 128; o > 0; o >>= 1) {
            if (tid < o) red[tid] |= red[tid + o];
            __syncthreads();
        }
        if (tid == 0) *flag = red[0] ? 1u : 0u;   // nonzero -> int32 storage
    } else if (b <= GN + 8) {
        wconv_block(W1, Wf1, b - GN - 1, tid);
    } else {
        wconv_block(W2, Wf2, b - GN - 9, tid);
    }
}

// ---------- fill: ONE u32 cursor atomic per edge + 4B bucket store ----------
// Runs ALONE: its cursor/bucket working set must own the L2 (r7/r12 lesson).
__global__ __launch_bounds__(256) void fill_kernel(
    const int* __restrict__ ei, const unsigned* __restrict__ flag,
    const float* __restrict__ ew, int* __restrict__ cursor, unsigned* __restrict__ bucket)
{
    int e = blockIdx.x * 256 + threadIdx.x;
    if (e < NE) {
        unsigned is32 = *flag;
        int s = ld_idx(ei, is32, e);
        int d = ld_idx(ei, is32, NE + e);
        unsigned wq = (unsigned)f2bf(ew[e]) & 0x7FFFu;   // bf16, sign bit 0
        int slot = atomicAdd(&cursor[d], 1);
        if (slot < CAP) bucket[(size_t)d * CAP + slot] = ((unsigned)s << 15) | wq;
    }
}

// ---------- unpack: weighted degree from buckets (coalesced), dinv, clamp cursor ----------
__global__ __launch_bounds__(256) void unpack_kernel(
    int* __restrict__ cursor, const unsigned* __restrict__ bucket, float* __restrict__ dinv)
{
    unsigned t = blockIdx.x * 256 + threadIdx.x;
    unsigned n = t >> 4;
    unsigned ln = t & 15;
    int c = cursor[n];
    if (c > CAP) c = CAP;
    float s = 0.f;
    const size_t base = (size_t)n * CAP;
    for (int i = (int)ln; i < c; i += 16) s += bfw(bucket[base + i]);
#pragma unroll
    for (int off = 8; off > 0; off >>= 1) s += __shfl_down(s, off, 16);
    if (ln == 0) {
        cursor[n] = c;
        dinv[n] = rsqrtf(s + 1.0f);
    }
}

// ---------- transposed MFMA gemm: H = (F32IN? diag(dinv):(I)) * (X @ W) ----------
// (X@W)^T = W^T @ X^T per 16x16 tile: A-frag = Wf, B-frag = X rows direct from global.
// D: lane holds 4 consecutive channels of one node -> 8B coalesced stores. No LDS/barrier.
template <bool F32IN>
__global__ __launch_bounds__(256) void gemmT_kernel(
    const void* __restrict__ Xv, const u16* __restrict__ Wf, u16* __restrict__ H,
    const float* __restrict__ dinv)
{
    const int tid = threadIdx.x;
    const int wave = tid >> 6, lane = tid & 63;
    const int m = lane & 15, q = lane >> 4;
    const unsigned nodeBase = blockIdx.x * 128 + wave * 32;

    U16x8 xf[2][4];
    float dn[2];
#pragma unroll
    for (int mt = 0; mt < 2; ++mt) {
        unsigned row = nodeBase + mt * 16 + m;
        unsigned rowc = row < NN ? row : NN - 1;
        if (F32IN) {
            dn[mt] = dinv[rowc];
#pragma unroll
            for (int kc = 0; kc < 4; ++kc) {
                float4 a = ((const float4*)Xv)[rowc * 32u + kc * 8 + q * 2];
                float4 b = ((const float4*)Xv)[rowc * 32u + kc * 8 + q * 2 + 1];
                xf[mt][kc].u = make_uint4(pack2(a.x, a.y), pack2(a.z, a.w),
                                          pack2(b.x, b.y), pack2(b.z, b.w));
            }
        } else {
#pragma unroll
            for (int kc = 0; kc < 4; ++kc)
                xf[mt][kc].u = ((const uint4*)Xv)[rowc * 16u + kc * 4 + q];
        }
    }

#pragma unroll
    for (int ct = 0; ct < 8; ++ct) {
        U16x8 wfr[4];
#pragma unroll
        for (int kc = 0; kc < 4; ++kc)
            wfr[kc].u = ((const uint4*)Wf)[(ct * 4 + kc) * 64 + lane];
#pragma unroll
        for (int mt = 0; mt < 2; ++mt) {
            f32x4 acc = (f32x4){0.f, 0.f, 0.f, 0.f};
#pragma unroll
            for (int kc = 0; kc < 4; ++kc)
                acc = __builtin_amdgcn_mfma_f32_16x16x32_bf16(
                    wfr[kc].h, xf[mt][kc].h, acc, 0, 0, 0);
            unsigned node = nodeBase + mt * 16 + m;
            if (node < NN) {
                float s = F32IN ? dn[mt] : 1.0f;
                uint2 o = make_uint2(pack2(acc[0] * s, acc[1] * s),
                                     pack2(acc[2] * s, acc[3] * s));
                *(uint2*)&H[(size_t)node * 128 + ct * 16 + q * 4] = o;
            }
        }
    }
}

// ---------- agg: 1 wave/node, straight-line 3 slots (deg<=12) + rare tail ----------
// lane = eo*16 + cg. row = dinv[n]*(sum w*H'[src] + H'[n]) + bias.
// Invalid slots: w=0, src:=n (wave-local hot row -> free). Self-loop issued early.
// HEAD=false: store relu(row)*dinv[n] bf16. HEAD=true: out[n] = relu(row).Wl + bl.
template <bool HEAD>
__global__ __launch_bounds__(256) void agg_kernel(
    const int* __restrict__ cnt, const unsigned* __restrict__ bucket,
    const u16* __restrict__ H, const float* __restrict__ dinv,
    const float* __restrict__ bias, const float* __restrict__ Wl,
    const float* __restrict__ bl, u16* __restrict__ X, float* __restrict__ out)
{
    unsigned t = blockIdx.x * 256 + threadIdx.x;
    unsigned n = t >> 6;
    unsigned lane = t & 63;
    unsigned cg = lane & 15;
    unsigned eo = lane >> 4;

    const int c = cnt[n];
    const unsigned base = n * CAP;
    const uint4* Hr = (const uint4*)H;

    // early issue: self-loop row + dinv (quarter-wave broadcast)
    uint4 hn = Hr[n * 16u + cg];
    float dnv = dinv[n];

    // slots eo, eo+4, eo+8 (max 11 < CAP); invalid -> w=0, src=n (already-hot row)
    unsigned e0 = bucket[base + eo];
    unsigned e1 = bucket[base + eo + 4];
    unsigned e2 = bucket[base + eo + 8];
    bool v0 = (int)eo < c, v1 = (int)eo + 4 < c, v2 = (int)eo + 8 < c;
    float w0 = v0 ? bfw(e0) : 0.f;
    float w1 = v1 ? bfw(e1) : 0.f;
    float w2 = v2 ? bfw(e2) : 0.f;
    unsigned s0 = v0 ? (e0 >> 15) : n;
    unsigned s1 = v1 ? (e1 >> 15) : n;
    unsigned s2 = v2 ? (e2 >> 15) : n;
    uint4 u0 = Hr[s0 * 16u + cg];
    uint4 u1 = Hr[s1 * 16u + cg];
    uint4 u2 = Hr[s2 * 16u + cg];

    f32x2 a0 = {0.f, 0.f}, a1 = {0.f, 0.f}, a2 = {0.f, 0.f}, a3 = {0.f, 0.f};
#define ACC4(U, WS)                                                     \
    {   f32x2 wv; wv.x = WS; wv.y = WS;                                 \
        a0 = __builtin_elementwise_fma(unpk2((U).x), wv, a0);           \
        a1 = __builtin_elementwise_fma(unpk2((U).y), wv, a1);           \
        a2 = __builtin_elementwise_fma(unpk2((U).z), wv, a2);           \
        a3 = __builtin_elementwise_fma(unpk2((U).w), wv, a3); }
    ACC4(u0, w0) ACC4(u1, w1) ACC4(u2, w2)

    if (c > 12) {                 // rare tail (~1% of nodes); entries valid -> no clamp
        for (int i = (int)eo + 12; i < c; i += 4) {
            unsigned e = bucket[base + i];
            float w = bfw(e);
            uint4 u = Hr[(e >> 15) * 16u + cg];
            ACC4(u, w)
        }
    }
#undef ACC4

    float acc[8] = {a0.x, a0.y, a1.x, a1.y, a2.x, a2.y, a3.x, a3.y};
#pragma unroll
    for (int j = 0; j < 8; ++j) {
        acc[j] += __shfl_down(acc[j], 32);
        acc[j] += __shfl_down(acc[j], 16);
    }

    float d = 0.f;
    if (lane < 16) {
        float4 b0 = ((const float4*)bias)[cg * 2];
        float4 b1 = ((const float4*)bias)[cg * 2 + 1];
        acc[0] += bflo(hn.x); acc[1] += bfhi(hn.x);
        acc[2] += bflo(hn.y); acc[3] += bfhi(hn.y);
        acc[4] += bflo(hn.z); acc[5] += bfhi(hn.z);
        acc[6] += bflo(hn.w); acc[7] += bfhi(hn.w);
        float v[8];
        v[0] = fmaxf(fmaf(dnv, acc[0], b0.x), 0.f);
        v[1] = fmaxf(fmaf(dnv, acc[1], b0.y), 0.f);
        v[2] = fmaxf(fmaf(dnv, acc[2], b0.z), 0.f);
        v[3] = fmaxf(fmaf(dnv, acc[3], b0.w), 0.f);
        v[4] = fmaxf(fmaf(dnv, acc[4], b1.x), 0.f);
        v[5] = fmaxf(fmaf(dnv, acc[5], b1.y), 0.f);
        v[6] = fmaxf(fmaf(dnv, acc[6], b1.z), 0.f);
        v[7] = fmaxf(fmaf(dnv, acc[7], b1.w), 0.f);
        if (HEAD) {
            float4 w0v = ((const float4*)Wl)[cg * 2];
            float4 w1v = ((const float4*)Wl)[cg * 2 + 1];
            d = v[0] * w0v.x + v[1] * w0v.y + v[2] * w0v.z + v[3] * w0v.w
              + v[4] * w1v.x + v[5] * w1v.y + v[6] * w1v.z + v[7] * w1v.w;
        } else {
            // store X1' = relu(row) * dinv[n]  (pre-scales gemm2's output)
            uint4 o;
            o.x = pack2(v[0] * dnv, v[1] * dnv); o.y = pack2(v[2] * dnv, v[3] * dnv);
            o.z = pack2(v[4] * dnv, v[5] * dnv); o.w = pack2(v[6] * dnv, v[7] * dnv);
            ((uint4*)X)[n * 16u + cg] = o;
        }
    }
    if (HEAD) {
#pragma unroll
        for (int off = 8; off > 0; off >>= 1) d += __shfl_down(d, off, 16);
        if (lane == 0) out[n] = d + bl[0];
    }
}

extern "C" void kernel_launch(void* const* d_in, const int* in_sizes, int n_in,
                              void* d_out, int out_size, void* d_ws, size_t ws_size,
                              hipStream_t stream) {
    const float* w_x = (const float*)d_in[0];
    const int*   ei  = (const int*)d_in[1];
    const float* ew  = (const float*)d_in[2];
    const float* W1  = (const float*)d_in[3];
    const float* b1  = (const float*)d_in[4];
    const float* W2  = (const float*)d_in[5];
    const float* b2  = (const float*)d_in[6];
    const float* Wl  = (const float*)d_in[7];
    const float* bl  = (const float*)d_in[8];
    float* out = (float*)d_out;

    // ws: H1[NN*128 bf16] H2[NN*128 bf16] Xb[NN*128 bf16] flag(+pad) dinv[NN]
    //     cursor[NN] bucket[NN*CAP u32] Wf1/Wf2[16384 u16]   (~91 MB)
    u16*      H1   = (u16*)d_ws;
    u16*      H2   = H1 + (size_t)NN * 128;
    u16*      Xb   = H2 + (size_t)NN * 128;
    unsigned* flag = (unsigned*)(Xb + (size_t)NN * 128);
    float*    dinv = (float*)(flag + 2);
    int*      cursor = (int*)(dinv + NN);
    unsigned* bucket = (unsigned*)(cursor + NN);
    u16*      Wf1  = (u16*)(bucket + (size_t)NN * CAP);
    u16*      Wf2  = Wf1 + 16384;

    const int BLK = 256;
    const int GA  = NN * 64 / BLK;     // 25000 agg blocks
    const int GU  = NN * 16 / BLK;     // 6250 unpack blocks

    init_kernel<<<GN + 17, BLK, 0, stream>>>(cursor, flag, (const unsigned*)ei,
                                             W1, W2, Wf1, Wf2);
    fill_kernel<<<FILLB, BLK, 0, stream>>>(ei, flag, ew, cursor, bucket);
    unpack_kernel<<<GU, BLK, 0, stream>>>(cursor, bucket, dinv);
    gemmT_kernel<true><<<GEMMB, BLK, 0, stream>>>(w_x, Wf1, H1, dinv);
    agg_kernel<false><<<GA, BLK, 0, stream>>>(cursor, bucket, H1, dinv, b1,
                                              nullptr, nullptr, Xb, nullptr);
    gemmT_kernel<false><<<GEMMB, BLK, 0, stream>>>(Xb, Wf2, H2, nullptr);
    agg_kernel<true><<<GA, BLK, 0, stream>>>(cursor, bucket, H2, dinv, b2,
                                             Wl, bl, nullptr, out);
}